// Round 5
// baseline (262.666 us; speedup 1.0000x reference)
//
#include <hip/hip_runtime.h>
#include <hip/hip_bf16.h>

// LinearAttention on MI355X. Pipeline (peak d_ws 66.3 MiB; K/V scratch in d_out):
//  xnorm_t (fused norm+transpose, x read ONCE) -> weight casts ->
//  gemm_bt<1536,split3> (Q->ws, K/V->d_out) -> attn_ctx -> attn_out ->
//  gemm_bt<512,+bias> (bf16 pre) -> norm_scale (fused norm+scale, pre read ONCE)
// MFMA = v_mfma_f32_16x16x32_bf16, layouts:
//  A: m=lane&15, k=(lane>>4)*8+j ; B: n=lane&15, k=(lane>>4)*8+j ;
//  C/D: col=lane&15, row=(lane>>4)*4+reg
// R10: attn split at the context boundary: attn_ctx (256 blocks, K/V reduction,
//  writes rescaled C^T[64][64] bf16 into the head's own dead V-slice head —
//  zero extra ws, no cross-block hazard) + attn_out (1024 blocks = 4/CU,
//  ~20KB LDS, Q-phase with 4x TLP of the old 1-block/CU kernel).
//  gemm_bt epilogue re-staged as [128][128] chunk-XOR (LDS 34816->32768 B ->
//  5 blocks/CU). ws layout: wob@0, wqb@512KiB (both before xnT@2.25MiB).

#define AS1 __attribute__((address_space(1)))
#define AS3 __attribute__((address_space(3)))

using short8 = __attribute__((ext_vector_type(8))) short;
using usht4  = __attribute__((ext_vector_type(4))) unsigned short;
using f32x2  = __attribute__((ext_vector_type(2))) float;
using f32x4  = __attribute__((ext_vector_type(4))) float;

__device__ __forceinline__ unsigned short f2bf(float f) {
  unsigned int u = __float_as_uint(f);
  u += 0x7fffu + ((u >> 16) & 1u);          // RNE
  return (unsigned short)(u >> 16);
}
__device__ __forceinline__ float bf2f(unsigned short s) {
  return __uint_as_float(((unsigned int)s) << 16);
}

// ---------------------------------------------------------------------------
// K1 (fused): per (b, 32-pos strip): load x[b][0:512][strip] into LDS while
// accumulating per-pos sumsq; r = sqrt(512)/max(||x||,1e-12); then write
// xn_T[b][pos][c] = bf16(x*r) transposed. x read ONCE total.
__global__ __launch_bounds__(256, 2)
void xnorm_t(const float* __restrict__ X, unsigned short* __restrict__ XT) {
  __shared__ float tile[512][34];
  __shared__ float part[32][33];
  __shared__ float rloc[32];
  const int t = threadIdx.x;
  const int b = blockIdx.x >> 5;
  const int pos0 = (blockIdx.x & 31) * 32;
  const int pr = t & 7, cr = t >> 3;            // pr: 4-pos chunk, cr: row in 32-group
  const float* xp = X + ((size_t)b * 512 + cr) * 1024 + pos0 + pr * 4;
  f32x4 ssq = {0.f, 0.f, 0.f, 0.f};
#pragma unroll
  for (int i = 0; i < 16; ++i) {
    f32x4 v = *(const f32x4*)(xp + (size_t)(i * 32) * 1024);
    ssq += v * v;
    f32x2 lo = {v.x, v.y}, hi = {v.z, v.w};
    *(f32x2*)(&tile[i * 32 + cr][pr * 4]) = lo;
    *(f32x2*)(&tile[i * 32 + cr][pr * 4 + 2]) = hi;
  }
  part[cr][pr * 4 + 0] = ssq.x;
  part[cr][pr * 4 + 1] = ssq.y;
  part[cr][pr * 4 + 2] = ssq.z;
  part[cr][pr * 4 + 3] = ssq.w;
  __syncthreads();
  if (t < 32) {
    float tot = 0.f;
#pragma unroll
    for (int j = 0; j < 32; ++j) tot += part[j][t];
    rloc[t] = 22.627416998f / fmaxf(sqrtf(tot), 1e-12f);
  }
  __syncthreads();
#pragma unroll
  for (int k = 0; k < 8; ++k) {
    const int idx = k * 256 + t;
    const int p = idx >> 6, c8 = idx & 63;      // one pos per wave, 64 c-chunks
    const float r = rloc[p];
    short8 v;
#pragma unroll
    for (int j = 0; j < 8; ++j) v[j] = (short)f2bf(tile[c8 * 8 + j][p] * r);
    *(short8*)(XT + ((size_t)b * 1024 + pos0 + p) * 512 + c8 * 8) = v;
  }
}

// ---------------------------------------------------------------------------
// K6 (fused): per (b, 64-pos strip): load pre[b][0:512][strip] (bf16) into LDS
// with per-pos sumsq; write out[b][c][p] = bf2f(pre)*r2[p]*g_out[c] (fp32).
__global__ __launch_bounds__(256, 2)
void norm_scale(const unsigned short* __restrict__ P, const float* __restrict__ G,
                float* __restrict__ O) {
  __shared__ unsigned short tile[512][68];
  __shared__ float part[2048];                  // [32][64]; then rloc = part[0:64]
  const int t = threadIdx.x;
  const int b = blockIdx.x >> 4;
  const int pos0 = (blockIdx.x & 15) * 64;
  const int pg = t & 7, cr = t >> 3;            // pg: 8-pos chunk, cr: row in 32-group
  const unsigned short* pp = P + ((size_t)b * 512 + cr) * 1024 + pos0 + pg * 8;
  float s[8] = {};
#pragma unroll
  for (int i = 0; i < 16; ++i) {
    short8 v = *(const short8*)(pp + (size_t)(i * 32) * 1024);
    usht4 lo = {(unsigned short)v[0], (unsigned short)v[1],
                (unsigned short)v[2], (unsigned short)v[3]};
    usht4 hi = {(unsigned short)v[4], (unsigned short)v[5],
                (unsigned short)v[6], (unsigned short)v[7]};
    *(usht4*)(&tile[i * 32 + cr][pg * 8]) = lo;
    *(usht4*)(&tile[i * 32 + cr][pg * 8 + 4]) = hi;
#pragma unroll
    for (int j = 0; j < 8; ++j) {
      const float f = bf2f((unsigned short)v[j]);
      s[j] += f * f;
    }
  }
#pragma unroll
  for (int j = 0; j < 8; ++j) part[cr * 64 + pg * 8 + j] = s[j];
  __syncthreads();
  if (t < 64) {
    float tot = 0.f;
#pragma unroll
    for (int j = 0; j < 32; ++j) tot += part[j * 64 + t];
    part[t] = 22.627416998f / fmaxf(sqrtf(tot), 1e-12f);   // rloc[t]
  }
  __syncthreads();
#pragma unroll
  for (int k = 0; k < 32; ++k) {
    const int idx = k * 256 + t;
    const int c = idx >> 4, p4 = idx & 15;
    usht4 v = *(const usht4*)(&tile[c][p4 * 4]);
    const float g = G[c];
    f32x4 o;
    o.x = bf2f(v.x) * part[p4 * 4 + 0] * g;
    o.y = bf2f(v.y) * part[p4 * 4 + 1] * g;
    o.z = bf2f(v.z) * part[p4 * 4 + 2] * g;
    o.w = bf2f(v.w) * part[p4 * 4 + 3] * g;
    *(f32x4*)(O + ((size_t)b * 512 + c) * 1024 + pos0 + p4 * 4) = o;
  }
}

// ---------------------------------------------------------------------------
// weight casts
__global__ __launch_bounds__(256, 4)
void cast_wqkv(const float* __restrict__ W, const float* __restrict__ g,
               unsigned short* __restrict__ O) {
  int i = blockIdx.x * 256 + threadIdx.x;      // 786432 total
  O[i] = f2bf(W[i] * g[i & 511]);
}
__global__ __launch_bounds__(256, 4)
void cast_w(const float* __restrict__ W, unsigned short* __restrict__ O, int n) {
  int i = blockIdx.x * 256 + threadIdx.x;
  if (i < n) O[i] = f2bf(W[i]);
}

// ---------------------------------------------------------------------------
// Shared GEMM (R5 structure): Out[b][m][n] = sum_k A[m][k]*Ball[b][n][k].
// A: [MTOT][512] bf16 ; Ball: [32][1024][512] bf16. 128x128 tile, BK=64.
// LDS XOR swizzle on staging; epilogue C-stage [128][128] chunk-XOR
// (chunk' = chunk ^ (row&7)) so total LDS = 32768 B -> 5 blocks/CU.
template <int MTOT, bool SPLIT3, bool BIAS>
__global__ __launch_bounds__(256, 2)
void gemm_bt(const unsigned short* __restrict__ A,
             const unsigned short* __restrict__ Ball,
             unsigned short* __restrict__ O0, unsigned short* __restrict__ O1,
             unsigned short* __restrict__ O2, const float* __restrict__ bias) {
  __shared__ char smem[32768];
  unsigned short* lA = (unsigned short*)smem;        // [128][64] swizzled
  unsigned short* lB = lA + 128 * 64;                // [128][64] swizzled
  const int t = threadIdx.x;
  const int lane = t & 63, w = t >> 6;
  const int wm = w >> 1, wn = w & 1;
  const int mt = blockIdx.x >> 3, nt = blockIdx.x & 7;
  const int b = blockIdx.y;
  const unsigned short* Ag = A + (size_t)(mt * 128) * 512;
  const unsigned short* Bg = Ball + ((size_t)b * 1024 + (size_t)nt * 128) * 512;
  const int scol = ((lane & 7) ^ (lane >> 3)) * 8;   // swizzled source chunk
  f32x4 acc[4][4] = {};

  for (int kt = 0; kt < 8; ++kt) {
    const unsigned short* As = Ag + kt * 64 + scol;
    const unsigned short* Bs = Bg + kt * 64 + scol;
#pragma unroll
    for (int i = 0; i < 4; ++i) {
      const int r = w * 32 + i * 8 + (lane >> 3);
      __builtin_amdgcn_global_load_lds(
          (const AS1 unsigned int*)(As + (size_t)r * 512),
          (AS3 unsigned int*)(lA + (w * 32 + i * 8) * 64), 16, 0, 0);
      __builtin_amdgcn_global_load_lds(
          (const AS1 unsigned int*)(Bs + (size_t)r * 512),
          (AS3 unsigned int*)(lB + (w * 32 + i * 8) * 64), 16, 0, 0);
    }
    __syncthreads();
#pragma unroll
    for (int ks = 0; ks < 2; ++ks) {
      const int pch = ((ks * 4 + (lane >> 4)) ^ (lane & 7)) * 8;  // row&7==lane&7
      short8 af[4], bfv[4];
#pragma unroll
      for (int i = 0; i < 4; ++i)
        af[i] = *(const short8*)(lA + (wm * 64 + i * 16 + (lane & 15)) * 64 + pch);
#pragma unroll
      for (int j = 0; j < 4; ++j)
        bfv[j] = *(const short8*)(lB + (wn * 64 + j * 16 + (lane & 15)) * 64 + pch);
#pragma unroll
      for (int i = 0; i < 4; ++i)
#pragma unroll
        for (int j = 0; j < 4; ++j)
          acc[i][j] = __builtin_amdgcn_mfma_f32_16x16x32_bf16(af[i], bfv[j],
                                                              acc[i][j], 0, 0, 0);
    }
    __syncthreads();
  }

  // epilogue: [128][128] chunk-XOR C stage, coalesced 16B streams out
  unsigned short* Cst = (unsigned short*)smem;
#pragma unroll
  for (int i = 0; i < 4; ++i)
#pragma unroll
    for (int j = 0; j < 4; ++j)
#pragma unroll
      for (int r = 0; r < 4; ++r) {
        const int row = wm * 64 + i * 16 + (lane >> 4) * 4 + r;
        const int col = wn * 64 + j * 16 + (lane & 15);
        float v = acc[i][j][r];
        if (BIAS) v += bias[mt * 128 + row];
        Cst[row * 128 + ((((col >> 3) ^ (row & 7)) << 3) | (col & 7))] = f2bf(v);
      }
  __syncthreads();
  unsigned short* Og;
  if (SPLIT3) {
    const int sec = mt >> 2;
    unsigned short* base = (sec == 0) ? O0 : ((sec == 1) ? O1 : O2);
    Og = base + ((size_t)b * 512 + (size_t)(mt & 3) * 128) * 1024 + (size_t)nt * 128;
  } else {
    Og = O0 + ((size_t)b * MTOT + (size_t)mt * 128) * 1024 + (size_t)nt * 128;
  }
#pragma unroll
  for (int k = 0; k < 8; ++k) {
    const int f = t + k * 256;
    const int row = f >> 4, c8 = f & 15;
    short8 v = *(const short8*)(Cst + row * 128 + ((c8 ^ (row & 7)) << 3));
    *(short8*)(Og + (size_t)row * 1024 + c8 * 8) = v;
  }
}

// ---------------------------------------------------------------------------
// K5a: context per (b,h): C_raw[d][e] = sum_n exp(K[d][n])*V[e][n] over
// mem+1024 cols; rowsum denominators; writes rescaled C^T[e][d] (bf16,
// [64][64]) into the head's own (now dead) V-slice: Vp + hb.
__global__ __launch_bounds__(256, 2)
void attn_ctx(const unsigned short* __restrict__ Kp,
              const unsigned short* __restrict__ Vp,
              const float* __restrict__ memkv,
              unsigned short* __restrict__ VpW) {
  __shared__ char smem[36608];
  unsigned short* bufA = (unsigned short*)smem;            // [64][72] expK
  unsigned short* bufB = (unsigned short*)(smem + 9216);   // [64][72] V / C^T
  float* Pl   = (float*)(smem + 18432);                    // [512] rowsum partials
  float* msum = (float*)(smem + 35072);                    // [64][4]
  float* rsI  = (float*)(smem + 36096);                    // [64]
  const int t = threadIdx.x;
  const int lane = t & 63, wave = t >> 6;
  const int b = blockIdx.x >> 3, h = blockIdx.x & 7;
  const size_t hb = ((size_t)b * 512 + (size_t)h * 64) * 1024;
  const unsigned short* Kg = Kp + hb;
  const unsigned short* Vg = Vp + hb;
  const float* mk = memkv + (size_t)h * 256;
  const float* mv = memkv + 2048 + (size_t)h * 256;

  float rsum[2] = {0.f, 0.f};
  f32x4 cacc[4] = {};

  for (int it = 0; it < 17; ++it) {
    if (it == 0) {                                   // mem tile (cols 0..3, rest 0)
      const int d = t & 63, j = t >> 6;
      const float ev = __expf(mk[d * 4 + j]);
      msum[d * 4 + j] = ev;
      bufA[d * 72 + j] = f2bf(ev);
      bufB[d * 72 + j] = f2bf(mv[d * 4 + j]);
      for (int c2 = 4 + j; c2 < 64; c2 += 4) {
        bufA[d * 72 + c2] = 0;
        bufB[d * 72 + c2] = 0;
      }
    } else {
      const int c0 = (it - 1) * 64;
#pragma unroll
      for (int z = 0; z < 2; ++z) {
        const int d = z * 32 + (t >> 3), ch = t & 7;
        short8 kv = *(const short8*)(Kg + (size_t)d * 1024 + c0 + ch * 8);
        short8 pk;
        float ssum = 0.f;
#pragma unroll
        for (int j = 0; j < 8; ++j) {
          const float e = __expf(bf2f((unsigned short)kv[j]));
          ssum += e;
          pk[j] = (short)f2bf(e);
        }
        rsum[z] += ssum;
        *(short8*)(bufA + d * 72 + ch * 8) = pk;
        short8 vv = *(const short8*)(Vg + (size_t)d * 1024 + c0 + ch * 8);
        *(short8*)(bufB + d * 72 + ch * 8) = vv;
      }
    }
    __syncthreads();
#pragma unroll
    for (int ks = 0; ks < 2; ++ks) {
      short8 a = *(const short8*)(bufA + (wave * 16 + (lane & 15)) * 72 +
                                  ks * 32 + (lane >> 4) * 8);
#pragma unroll
      for (int et = 0; et < 4; ++et) {
        short8 bb = *(const short8*)(bufB + (et * 16 + (lane & 15)) * 72 +
                                     ks * 32 + (lane >> 4) * 8);
        cacc[et] = __builtin_amdgcn_mfma_f32_16x16x32_bf16(a, bb, cacc[et], 0, 0, 0);
      }
    }
    __syncthreads();
  }

  // rowsum reduce (k softmax denominators)
  Pl[t]       = rsum[0];
  Pl[256 + t] = rsum[1];
  __syncthreads();
  if (t < 64) {
    float s = 0.f;
#pragma unroll
    for (int ch = 0; ch < 8; ++ch) s += Pl[t * 8 + ch];
    s += msum[t * 4] + msum[t * 4 + 1] + msum[t * 4 + 2] + msum[t * 4 + 3];
    rsI[t] = 1.0f / s;
  }
  __syncthreads();

  // C^T into LDS (bf16), folding 1/rowsum[d]
  unsigned short* CT = bufB;                         // staged V is dead
#pragma unroll
  for (int et = 0; et < 4; ++et)
#pragma unroll
    for (int r = 0; r < 4; ++r) {
      const int d = wave * 16 + (lane >> 4) * 4 + r;
      const int e = et * 16 + (lane & 15);
      CT[e * 72 + d] = f2bf(cacc[et][r] * rsI[d]);
    }
  __syncthreads();

  // coalesced C^T -> global (into own V-slice head: all V reads are done)
  unsigned short* ctxG = VpW + hb;                   // [64][64]
#pragma unroll
  for (int k = 0; k < 2; ++k) {
    const int idx = k * 256 + t;
    const int e = idx >> 3, ch = idx & 7;
    short8 v = *(const short8*)(CT + e * 72 + ch * 8);
    *(short8*)(ctxG + e * 64 + ch * 8) = v;
  }
}

// ---------------------------------------------------------------------------
// K5b: out[e][p] = sum_d C^T[e][d]*expQ[d][p] * scale/colsum[p], per
// (b,h,4-pt chunk): 1024 blocks (4/CU). C^T read from the V-slice head.
__global__ __launch_bounds__(256, 4)
void attn_out(const unsigned short* __restrict__ Qp,
              const unsigned short* __restrict__ ctxP,
              unsigned short* __restrict__ outT) {
  __shared__ unsigned short ctx[64 * 72];            // C^T
  __shared__ unsigned short eq[64 * 72];             // expQ^T
  __shared__ float Pc[256];
  __shared__ float csS[64];
  const int t = threadIdx.x;
  const int lane = t & 63, wave = t >> 6;
  const int b = blockIdx.x >> 5, h = (blockIdx.x >> 2) & 7, ptc = blockIdx.x & 3;
  const size_t hb = ((size_t)b * 512 + (size_t)h * 64) * 1024;
  const unsigned short* Qg = Qp + hb;
  const unsigned short* ctxG = ctxP + hb;            // [64][64]

#pragma unroll
  for (int k = 0; k < 2; ++k) {
    const int idx = k * 256 + t;
    const int e = idx >> 3, ch = idx & 7;
    short8 v = *(const short8*)(ctxG + e * 64 + ch * 8);
    *(short8*)(ctx + e * 72 + ch * 8) = v;
  }
  __syncthreads();

  short8 a0 = *(const short8*)(ctx + (wave * 16 + (lane & 15)) * 72 + (lane >> 4) * 8);
  short8 a1 = *(const short8*)(ctx + (wave * 16 + (lane & 15)) * 72 + 32 + (lane >> 4) * 8);
  unsigned short* oBase = outT + (size_t)b * 1024 * 512 + h * 64;

  for (int it = 0; it < 4; ++it) {
    const int pt = ptc * 4 + it;
    {
      const int p = lane, dq = wave;
      float cp = 0.f;
#pragma unroll
      for (int i2 = 0; i2 < 8; ++i2) {
        const int d0 = dq * 16 + i2 * 2;
        const float e0 = __expf(bf2f(Qg[(size_t)d0 * 1024 + pt * 64 + p]));
        const float e1 = __expf(bf2f(Qg[(size_t)(d0 + 1) * 1024 + pt * 64 + p]));
        cp += e0 + e1;
        const unsigned int pk =
            (unsigned int)f2bf(e0) | ((unsigned int)f2bf(e1) << 16);
        *(unsigned int*)(eq + p * 72 + d0) = pk;     // expQ^T[p][d]
      }
      Pc[dq * 64 + p] = cp;
    }
    __syncthreads();
    if (t < 64) csS[t] = 0.125f / (Pc[t] + Pc[64 + t] + Pc[128 + t] + Pc[192 + t]);
    __syncthreads();
#pragma unroll
    for (int ps = 0; ps < 4; ++ps) {
      f32x4 oc = {};
      short8 b0 = *(const short8*)(eq + (ps * 16 + (lane & 15)) * 72 + (lane >> 4) * 8);
      short8 b1 = *(const short8*)(eq + (ps * 16 + (lane & 15)) * 72 + 32 + (lane >> 4) * 8);
      oc = __builtin_amdgcn_mfma_f32_16x16x32_bf16(a0, b0, oc, 0, 0, 0);
      oc = __builtin_amdgcn_mfma_f32_16x16x32_bf16(a1, b1, oc, 0, 0, 0);
      const float cs = csS[ps * 16 + (lane & 15)];
      const unsigned long long pk =
          (unsigned long long)f2bf(oc[0] * cs) |
          ((unsigned long long)f2bf(oc[1] * cs) << 16) |
          ((unsigned long long)f2bf(oc[2] * cs) << 32) |
          ((unsigned long long)f2bf(oc[3] * cs) << 48);
      const int p = pt * 64 + ps * 16 + (lane & 15);
      *(unsigned long long*)(oBase + (size_t)p * 512 + wave * 16 + (lane >> 4) * 4) = pk;
    }
    __syncthreads();
  }
}

// ---------------------------------------------------------------------------
extern "C" void kernel_launch(void* const* d_in, const int* in_sizes, int n_in,
                              void* d_out, int out_size, void* d_ws, size_t ws_size,
                              hipStream_t stream) {
  (void)in_sizes; (void)n_in; (void)out_size; (void)ws_size;
  const float* x     = (const float*)d_in[0];
  const float* g_in  = (const float*)d_in[1];
  const float* w_qkv = (const float*)d_in[2];
  const float* memkv = (const float*)d_in[3];
  const float* w_out = (const float*)d_in[4];
  const float* b_out = (const float*)d_in[5];
  const float* g_out = (const float*)d_in[6];
  float* out = (float*)d_out;

  // d_ws layout — peak 69,468,160 B (66.3 MiB)
  char* ws = (char*)d_ws;
  unsigned short* wob = (unsigned short*)ws;               // 0.5 MiB @ 0
  unsigned short* wqb = (unsigned short*)(ws + 524288);    // 1.5 MiB @ 512K
  unsigned short* xnT = (unsigned short*)(ws + 2359296);   // 32 MiB (→ outT)
  unsigned short* Qp  = (unsigned short*)(ws + 35913728);  // 32 MiB (→ pre)
  unsigned short* outT = xnT;
  unsigned short* pre  = Qp;
  // K/V live in d_out (exactly 64 MiB); d_out fully rewritten by norm_scale.
  // ctx (rescaled C^T per head, 8 KB) reuses each head's dead V-slice.
  unsigned short* Kp  = (unsigned short*)d_out;
  unsigned short* Vp  = (unsigned short*)d_out + 16777216;

  xnorm_t<<<1024, 256, 0, stream>>>(x, xnT);
  cast_wqkv<<<3072, 256, 0, stream>>>(w_qkv, g_in, wqb);
  cast_w<<<1024, 256, 0, stream>>>(w_out, wob, 262144);
  gemm_bt<1536, true, false><<<dim3(96, 32), 256, 0, stream>>>(
      wqb, xnT, Qp, Kp, Vp, nullptr);
  attn_ctx<<<256, 256, 0, stream>>>(Kp, Vp, memkv, Vp);
  attn_out<<<1024, 256, 0, stream>>>(Qp, Vp, outT);
  gemm_bt<512, false, true><<<dim3(32, 32), 256, 0, stream>>>(
      wob, outT, pre, nullptr, nullptr, b_out);
  norm_scale<<<512, 256, 0, stream>>>(pre, g_out, out);
}

// Round 6
// 254.639 us; speedup vs baseline: 1.0315x; 1.0315x over previous
//
#include <hip/hip_runtime.h>
#include <hip/hip_bf16.h>

// LinearAttention on MI355X. Pipeline (peak d_ws 66.3 MiB; K/V scratch in d_out):
//  xnorm_t (fused norm+transpose, x read ONCE) -> weight casts ->
//  gemm_bt<1536,split3> (Q->ws, K/V->d_out) -> attn_kernel ->
//  gemm_bt<512,+bias> (bf16 pre) -> norm_scale (fused norm+scale, pre read ONCE)
// MFMA = v_mfma_f32_16x16x32_bf16, layouts:
//  A: m=lane&15, k=(lane>>4)*8+j ; B: n=lane&15, k=(lane>>4)*8+j ;
//  C/D: col=lane&15, row=(lane>>4)*4+reg
// R11: attn split (R10) reverted -- single attn kernel again, but with T14
//  register prefetch: K/V tile it+1 loaded into regs while tile it is
//  exp'd/MFMA'd (global-load latency hides under VALU+barriers+MFMA);
//  same 1-ahead prefetch in the Q phase; s_setprio(1) around MFMA clusters.
//  gemm_bt keeps R10's conflict-free [128][128] chunk-XOR epilogue (32KiB LDS).

#define AS1 __attribute__((address_space(1)))
#define AS3 __attribute__((address_space(3)))

using short8 = __attribute__((ext_vector_type(8))) short;
using usht4  = __attribute__((ext_vector_type(4))) unsigned short;
using f32x2  = __attribute__((ext_vector_type(2))) float;
using f32x4  = __attribute__((ext_vector_type(4))) float;

__device__ __forceinline__ unsigned short f2bf(float f) {
  unsigned int u = __float_as_uint(f);
  u += 0x7fffu + ((u >> 16) & 1u);          // RNE
  return (unsigned short)(u >> 16);
}
__device__ __forceinline__ float bf2f(unsigned short s) {
  return __uint_as_float(((unsigned int)s) << 16);
}

// ---------------------------------------------------------------------------
// K1 (fused): per (b, 32-pos strip): load x[b][0:512][strip] into LDS while
// accumulating per-pos sumsq; r = sqrt(512)/max(||x||,1e-12); then write
// xn_T[b][pos][c] = bf16(x*r) transposed. x read ONCE total.
__global__ __launch_bounds__(256, 2)
void xnorm_t(const float* __restrict__ X, unsigned short* __restrict__ XT) {
  __shared__ float tile[512][34];
  __shared__ float part[32][33];
  __shared__ float rloc[32];
  const int t = threadIdx.x;
  const int b = blockIdx.x >> 5;
  const int pos0 = (blockIdx.x & 31) * 32;
  const int pr = t & 7, cr = t >> 3;            // pr: 4-pos chunk, cr: row in 32-group
  const float* xp = X + ((size_t)b * 512 + cr) * 1024 + pos0 + pr * 4;
  f32x4 ssq = {0.f, 0.f, 0.f, 0.f};
#pragma unroll
  for (int i = 0; i < 16; ++i) {
    f32x4 v = *(const f32x4*)(xp + (size_t)(i * 32) * 1024);
    ssq += v * v;
    f32x2 lo = {v.x, v.y}, hi = {v.z, v.w};
    *(f32x2*)(&tile[i * 32 + cr][pr * 4]) = lo;
    *(f32x2*)(&tile[i * 32 + cr][pr * 4 + 2]) = hi;
  }
  part[cr][pr * 4 + 0] = ssq.x;
  part[cr][pr * 4 + 1] = ssq.y;
  part[cr][pr * 4 + 2] = ssq.z;
  part[cr][pr * 4 + 3] = ssq.w;
  __syncthreads();
  if (t < 32) {
    float tot = 0.f;
#pragma unroll
    for (int j = 0; j < 32; ++j) tot += part[j][t];
    rloc[t] = 22.627416998f / fmaxf(sqrtf(tot), 1e-12f);
  }
  __syncthreads();
#pragma unroll
  for (int k = 0; k < 8; ++k) {
    const int idx = k * 256 + t;
    const int p = idx >> 6, c8 = idx & 63;      // one pos per wave, 64 c-chunks
    const float r = rloc[p];
    short8 v;
#pragma unroll
    for (int j = 0; j < 8; ++j) v[j] = (short)f2bf(tile[c8 * 8 + j][p] * r);
    *(short8*)(XT + ((size_t)b * 1024 + pos0 + p) * 512 + c8 * 8) = v;
  }
}

// ---------------------------------------------------------------------------
// K6 (fused): per (b, 64-pos strip): load pre[b][0:512][strip] (bf16) into LDS
// with per-pos sumsq; write out[b][c][p] = bf2f(pre)*r2[p]*g_out[c] (fp32).
__global__ __launch_bounds__(256, 2)
void norm_scale(const unsigned short* __restrict__ P, const float* __restrict__ G,
                float* __restrict__ O) {
  __shared__ unsigned short tile[512][68];
  __shared__ float part[2048];                  // [32][64]; then rloc = part[0:64]
  const int t = threadIdx.x;
  const int b = blockIdx.x >> 4;
  const int pos0 = (blockIdx.x & 15) * 64;
  const int pg = t & 7, cr = t >> 3;            // pg: 8-pos chunk, cr: row in 32-group
  const unsigned short* pp = P + ((size_t)b * 512 + cr) * 1024 + pos0 + pg * 8;
  float s[8] = {};
#pragma unroll
  for (int i = 0; i < 16; ++i) {
    short8 v = *(const short8*)(pp + (size_t)(i * 32) * 1024);
    usht4 lo = {(unsigned short)v[0], (unsigned short)v[1],
                (unsigned short)v[2], (unsigned short)v[3]};
    usht4 hi = {(unsigned short)v[4], (unsigned short)v[5],
                (unsigned short)v[6], (unsigned short)v[7]};
    *(usht4*)(&tile[i * 32 + cr][pg * 8]) = lo;
    *(usht4*)(&tile[i * 32 + cr][pg * 8 + 4]) = hi;
#pragma unroll
    for (int j = 0; j < 8; ++j) {
      const float f = bf2f((unsigned short)v[j]);
      s[j] += f * f;
    }
  }
#pragma unroll
  for (int j = 0; j < 8; ++j) part[cr * 64 + pg * 8 + j] = s[j];
  __syncthreads();
  if (t < 64) {
    float tot = 0.f;
#pragma unroll
    for (int j = 0; j < 32; ++j) tot += part[j * 64 + t];
    part[t] = 22.627416998f / fmaxf(sqrtf(tot), 1e-12f);   // rloc[t]
  }
  __syncthreads();
#pragma unroll
  for (int k = 0; k < 32; ++k) {
    const int idx = k * 256 + t;
    const int c = idx >> 4, p4 = idx & 15;
    usht4 v = *(const usht4*)(&tile[c][p4 * 4]);
    const float g = G[c];
    f32x4 o;
    o.x = bf2f(v.x) * part[p4 * 4 + 0] * g;
    o.y = bf2f(v.y) * part[p4 * 4 + 1] * g;
    o.z = bf2f(v.z) * part[p4 * 4 + 2] * g;
    o.w = bf2f(v.w) * part[p4 * 4 + 3] * g;
    *(f32x4*)(O + ((size_t)b * 512 + c) * 1024 + pos0 + p4 * 4) = o;
  }
}

// ---------------------------------------------------------------------------
// weight casts
__global__ __launch_bounds__(256, 4)
void cast_wqkv(const float* __restrict__ W, const float* __restrict__ g,
               unsigned short* __restrict__ O) {
  int i = blockIdx.x * 256 + threadIdx.x;      // 786432 total
  O[i] = f2bf(W[i] * g[i & 511]);
}
__global__ __launch_bounds__(256, 4)
void cast_w(const float* __restrict__ W, unsigned short* __restrict__ O, int n) {
  int i = blockIdx.x * 256 + threadIdx.x;
  if (i < n) O[i] = f2bf(W[i]);
}

// ---------------------------------------------------------------------------
// Shared GEMM (R5 structure + R10 epilogue): Out[b][m][n] = sum_k A[m][k]*Ball[b][n][k].
// A: [MTOT][512] bf16 ; Ball: [32][1024][512] bf16. 128x128 tile, BK=64.
// LDS XOR swizzle on staging; epilogue C-stage [128][128] chunk-XOR
// (chunk' = chunk ^ (row&7)) so total LDS = 32768 B.
template <int MTOT, bool SPLIT3, bool BIAS>
__global__ __launch_bounds__(256, 2)
void gemm_bt(const unsigned short* __restrict__ A,
             const unsigned short* __restrict__ Ball,
             unsigned short* __restrict__ O0, unsigned short* __restrict__ O1,
             unsigned short* __restrict__ O2, const float* __restrict__ bias) {
  __shared__ char smem[32768];
  unsigned short* lA = (unsigned short*)smem;        // [128][64] swizzled
  unsigned short* lB = lA + 128 * 64;                // [128][64] swizzled
  const int t = threadIdx.x;
  const int lane = t & 63, w = t >> 6;
  const int wm = w >> 1, wn = w & 1;
  const int mt = blockIdx.x >> 3, nt = blockIdx.x & 7;
  const int b = blockIdx.y;
  const unsigned short* Ag = A + (size_t)(mt * 128) * 512;
  const unsigned short* Bg = Ball + ((size_t)b * 1024 + (size_t)nt * 128) * 512;
  const int scol = ((lane & 7) ^ (lane >> 3)) * 8;   // swizzled source chunk
  f32x4 acc[4][4] = {};

  for (int kt = 0; kt < 8; ++kt) {
    const unsigned short* As = Ag + kt * 64 + scol;
    const unsigned short* Bs = Bg + kt * 64 + scol;
#pragma unroll
    for (int i = 0; i < 4; ++i) {
      const int r = w * 32 + i * 8 + (lane >> 3);
      __builtin_amdgcn_global_load_lds(
          (const AS1 unsigned int*)(As + (size_t)r * 512),
          (AS3 unsigned int*)(lA + (w * 32 + i * 8) * 64), 16, 0, 0);
      __builtin_amdgcn_global_load_lds(
          (const AS1 unsigned int*)(Bs + (size_t)r * 512),
          (AS3 unsigned int*)(lB + (w * 32 + i * 8) * 64), 16, 0, 0);
    }
    __syncthreads();
#pragma unroll
    for (int ks = 0; ks < 2; ++ks) {
      const int pch = ((ks * 4 + (lane >> 4)) ^ (lane & 7)) * 8;  // row&7==lane&7
      short8 af[4], bfv[4];
#pragma unroll
      for (int i = 0; i < 4; ++i)
        af[i] = *(const short8*)(lA + (wm * 64 + i * 16 + (lane & 15)) * 64 + pch);
#pragma unroll
      for (int j = 0; j < 4; ++j)
        bfv[j] = *(const short8*)(lB + (wn * 64 + j * 16 + (lane & 15)) * 64 + pch);
#pragma unroll
      for (int i = 0; i < 4; ++i)
#pragma unroll
        for (int j = 0; j < 4; ++j)
          acc[i][j] = __builtin_amdgcn_mfma_f32_16x16x32_bf16(af[i], bfv[j],
                                                              acc[i][j], 0, 0, 0);
    }
    __syncthreads();
  }

  // epilogue: [128][128] chunk-XOR C stage, coalesced 16B streams out
  unsigned short* Cst = (unsigned short*)smem;
#pragma unroll
  for (int i = 0; i < 4; ++i)
#pragma unroll
    for (int j = 0; j < 4; ++j)
#pragma unroll
      for (int r = 0; r < 4; ++r) {
        const int row = wm * 64 + i * 16 + (lane >> 4) * 4 + r;
        const int col = wn * 64 + j * 16 + (lane & 15);
        float v = acc[i][j][r];
        if (BIAS) v += bias[mt * 128 + row];
        Cst[row * 128 + ((((col >> 3) ^ (row & 7)) << 3) | (col & 7))] = f2bf(v);
      }
  __syncthreads();
  unsigned short* Og;
  if (SPLIT3) {
    const int sec = mt >> 2;
    unsigned short* base = (sec == 0) ? O0 : ((sec == 1) ? O1 : O2);
    Og = base + ((size_t)b * 512 + (size_t)(mt & 3) * 128) * 1024 + (size_t)nt * 128;
  } else {
    Og = O0 + ((size_t)b * MTOT + (size_t)mt * 128) * 1024 + (size_t)nt * 128;
  }
#pragma unroll
  for (int k = 0; k < 8; ++k) {
    const int f = t + k * 256;
    const int row = f >> 4, c8 = f & 15;
    short8 v = *(const short8*)(Cst + row * 128 + ((c8 ^ (row & 7)) << 3));
    *(short8*)(Og + (size_t)row * 1024 + c8 * 8) = v;
  }
}

// ---------------------------------------------------------------------------
// K5: attention per (b,h). Q/K/V: [32][512][1024] bf16 each.
// outT: [32][1024][512] bf16.  R11: T14 register prefetch (K/V tile it+1
// loaded while tile it computes; Q pt+1 loaded while pt computes) + setprio.
__global__ __launch_bounds__(256, 2)
void attn_kernel(const unsigned short* __restrict__ Qp,
                 const unsigned short* __restrict__ Kp,
                 const unsigned short* __restrict__ Vp,
                 const float* __restrict__ memkv,
                 unsigned short* __restrict__ outT) {
  __shared__ char smem[36608];
  unsigned short* bufA = (unsigned short*)smem;            // [64][72] expK / expQ^T
  unsigned short* bufB = (unsigned short*)(smem + 9216);   // [64][72] V / C^T
  float* Pl   = (float*)(smem + 18432);                    // [512] rowsum partials
  float* Pc   = (float*)(smem + 18432);                    // [4][64] colsum (Q phase)
  float* csS  = (float*)(smem + 21504);                    // [64]
  float* msum = (float*)(smem + 35072);                    // [64][4]
  float* rsI  = (float*)(smem + 36096);                    // [64]
  const int t = threadIdx.x;
  const int lane = t & 63, wave = t >> 6;
  const int b = blockIdx.x >> 3, h = blockIdx.x & 7;
  const size_t hb = ((size_t)b * 512 + (size_t)h * 64) * 1024;
  const unsigned short* Qg = Qp + hb;
  const unsigned short* Kg = Kp + hb;
  const unsigned short* Vg = Vp + hb;
  const float* mk = memkv + (size_t)h * 256;
  const float* mv = memkv + 2048 + (size_t)h * 256;

  float rsum[2] = {0.f, 0.f};
  f32x4 cacc[4] = {};

  // prefetch pointers for the K/V loop: thread handles rows dz and 32+dz, chunk ch
  const int dz = t >> 3, ch = t & 7;
  const unsigned short* Kr0 = Kg + (size_t)dz * 1024 + ch * 8;
  const unsigned short* Kr1 = Kg + (size_t)(32 + dz) * 1024 + ch * 8;
  const unsigned short* Vr0 = Vg + (size_t)dz * 1024 + ch * 8;
  const unsigned short* Vr1 = Vg + (size_t)(32 + dz) * 1024 + ch * 8;
  short8 kr0 = *(const short8*)(Kr0);      // tile for it=1 (c0=0)
  short8 kr1 = *(const short8*)(Kr1);
  short8 vr0 = *(const short8*)(Vr0);
  short8 vr1 = *(const short8*)(Vr1);

  // ---- context: C_raw[d][e] = sum_n exp(K[d][n]) * V[e][n], n over mem+1024
  for (int it = 0; it < 17; ++it) {
    if (it == 0) {                                   // mem tile (cols 0..3, rest 0)
      const int d = t & 63, j = t >> 6;
      const float ev = __expf(mk[d * 4 + j]);
      msum[d * 4 + j] = ev;
      bufA[d * 72 + j] = f2bf(ev);
      bufB[d * 72 + j] = f2bf(mv[d * 4 + j]);
      for (int c2 = 4 + j; c2 < 64; c2 += 4) {
        bufA[d * 72 + c2] = 0;
        bufB[d * 72 + c2] = 0;
      }
    } else {
      short8 k0 = kr0, k1 = kr1, v0 = vr0, v1 = vr1;   // regs of tile `it`
      if (it < 16) {                                   // issue tile it+1 loads
        const int c0n = it * 64;
        kr0 = *(const short8*)(Kr0 + c0n);
        kr1 = *(const short8*)(Kr1 + c0n);
        vr0 = *(const short8*)(Vr0 + c0n);
        vr1 = *(const short8*)(Vr1 + c0n);
      }
      {
        short8 pk; float ss = 0.f;
#pragma unroll
        for (int j = 0; j < 8; ++j) {
          const float e = __expf(bf2f((unsigned short)k0[j]));
          ss += e;
          pk[j] = (short)f2bf(e);
        }
        rsum[0] += ss;
        *(short8*)(bufA + dz * 72 + ch * 8) = pk;
        *(short8*)(bufB + dz * 72 + ch * 8) = v0;
      }
      {
        short8 pk; float ss = 0.f;
#pragma unroll
        for (int j = 0; j < 8; ++j) {
          const float e = __expf(bf2f((unsigned short)k1[j]));
          ss += e;
          pk[j] = (short)f2bf(e);
        }
        rsum[1] += ss;
        *(short8*)(bufA + (32 + dz) * 72 + ch * 8) = pk;
        *(short8*)(bufB + (32 + dz) * 72 + ch * 8) = v1;
      }
    }
    __syncthreads();
    __builtin_amdgcn_s_setprio(1);
#pragma unroll
    for (int ks = 0; ks < 2; ++ks) {
      short8 a = *(const short8*)(bufA + (wave * 16 + (lane & 15)) * 72 +
                                  ks * 32 + (lane >> 4) * 8);
#pragma unroll
      for (int et = 0; et < 4; ++et) {
        short8 bb = *(const short8*)(bufB + (et * 16 + (lane & 15)) * 72 +
                                     ks * 32 + (lane >> 4) * 8);
        cacc[et] = __builtin_amdgcn_mfma_f32_16x16x32_bf16(a, bb, cacc[et], 0, 0, 0);
      }
    }
    __builtin_amdgcn_s_setprio(0);
    __syncthreads();
  }

  // ---- rowsum reduce (k softmax denominators): Pl[(d,ch)] = partial
  Pl[t]       = rsum[0];     // d = t>>3, ch = t&7  -> index d*8+ch = t
  Pl[256 + t] = rsum[1];
  __syncthreads();
  if (t < 64) {
    float s = 0.f;
#pragma unroll
    for (int ch2 = 0; ch2 < 8; ++ch2) s += Pl[t * 8 + ch2];
    s += msum[t * 4] + msum[t * 4 + 1] + msum[t * 4 + 2] + msum[t * 4 + 3];
    rsI[t] = 1.0f / s;
  }
  __syncthreads();

  // ---- C^T into LDS (bf16), folding 1/rowsum[d]
  unsigned short* CT = bufB;                         // staged V is dead
#pragma unroll
  for (int et = 0; et < 4; ++et)
#pragma unroll
    for (int r = 0; r < 4; ++r) {
      const int d = wave * 16 + (lane >> 4) * 4 + r;
      const int e = et * 16 + (lane & 15);
      CT[e * 72 + d] = f2bf(cacc[et][r] * rsI[d]);
    }
  __syncthreads();

  short8 a0 = *(const short8*)(CT + (wave * 16 + (lane & 15)) * 72 + (lane >> 4) * 8);
  short8 a1 = *(const short8*)(CT + (wave * 16 + (lane & 15)) * 72 + 32 + (lane >> 4) * 8);
  unsigned short* oBase = outT + (size_t)b * 1024 * 512 + h * 64;

  // ---- out[e][p] = sum_d C^T[e][d]*expQ[d][p] * scale/colsum[p]
  // Q prefetch: thread (wave,lane) owns rows dq*16+0..15, col pt*64+p
  const int p = lane, dq = wave;
  unsigned short qv[16];
#pragma unroll
  for (int i2 = 0; i2 < 8; ++i2) {
    qv[2 * i2]     = Qg[(size_t)(dq * 16 + i2 * 2) * 1024 + p];
    qv[2 * i2 + 1] = Qg[(size_t)(dq * 16 + i2 * 2 + 1) * 1024 + p];
  }
  for (int pt = 0; pt < 16; ++pt) {
    unsigned short q[16];
#pragma unroll
    for (int j = 0; j < 16; ++j) q[j] = qv[j];
    if (pt < 15) {
      const int qo = (pt + 1) * 64;
#pragma unroll
      for (int i2 = 0; i2 < 8; ++i2) {
        qv[2 * i2]     = Qg[(size_t)(dq * 16 + i2 * 2) * 1024 + qo + p];
        qv[2 * i2 + 1] = Qg[(size_t)(dq * 16 + i2 * 2 + 1) * 1024 + qo + p];
      }
    }
    {
      float cp = 0.f;
#pragma unroll
      for (int i2 = 0; i2 < 8; ++i2) {
        const int d0 = dq * 16 + i2 * 2;
        const float e0 = __expf(bf2f(q[2 * i2]));
        const float e1 = __expf(bf2f(q[2 * i2 + 1]));
        cp += e0 + e1;
        const unsigned int pk =
            (unsigned int)f2bf(e0) | ((unsigned int)f2bf(e1) << 16);
        *(unsigned int*)(bufA + p * 72 + d0) = pk;   // expQ^T[p][d]
      }
      Pc[dq * 64 + p] = cp;
    }
    __syncthreads();
    if (t < 64) csS[t] = 0.125f / (Pc[t] + Pc[64 + t] + Pc[128 + t] + Pc[192 + t]);
    __syncthreads();
    __builtin_amdgcn_s_setprio(1);
#pragma unroll
    for (int ps = 0; ps < 4; ++ps) {
      f32x4 oc = {};
      short8 b0 = *(const short8*)(bufA + (ps * 16 + (lane & 15)) * 72 + (lane >> 4) * 8);
      short8 b1 = *(const short8*)(bufA + (ps * 16 + (lane & 15)) * 72 + 32 + (lane >> 4) * 8);
      oc = __builtin_amdgcn_mfma_f32_16x16x32_bf16(a0, b0, oc, 0, 0, 0);
      oc = __builtin_amdgcn_mfma_f32_16x16x32_bf16(a1, b1, oc, 0, 0, 0);
      const float cs = csS[ps * 16 + (lane & 15)];
      const unsigned long long pk =
          (unsigned long long)f2bf(oc[0] * cs) |
          ((unsigned long long)f2bf(oc[1] * cs) << 16) |
          ((unsigned long long)f2bf(oc[2] * cs) << 32) |
          ((unsigned long long)f2bf(oc[3] * cs) << 48);
      const int pp2 = pt * 64 + ps * 16 + (lane & 15);
      *(unsigned long long*)(oBase + (size_t)pp2 * 512 + wave * 16 + (lane >> 4) * 4) = pk;
    }
    __builtin_amdgcn_s_setprio(0);
    __syncthreads();
  }
}

// ---------------------------------------------------------------------------
extern "C" void kernel_launch(void* const* d_in, const int* in_sizes, int n_in,
                              void* d_out, int out_size, void* d_ws, size_t ws_size,
                              hipStream_t stream) {
  (void)in_sizes; (void)n_in; (void)out_size; (void)ws_size;
  const float* x     = (const float*)d_in[0];
  const float* g_in  = (const float*)d_in[1];
  const float* w_qkv = (const float*)d_in[2];
  const float* memkv = (const float*)d_in[3];
  const float* w_out = (const float*)d_in[4];
  const float* b_out = (const float*)d_in[5];
  const float* g_out = (const float*)d_in[6];
  float* out = (float*)d_out;

  // d_ws layout — peak 69,468,160 B (66.3 MiB)
  char* ws = (char*)d_ws;
  unsigned short* wob = (unsigned short*)ws;               // 0.5 MiB @ 0
  unsigned short* wqb = (unsigned short*)(ws + 524288);    // 1.5 MiB @ 512K
  unsigned short* xnT = (unsigned short*)(ws + 2359296);   // 32 MiB (→ outT)
  unsigned short* Qp  = (unsigned short*)(ws + 35913728);  // 32 MiB (→ pre)
  unsigned short* outT = xnT;
  unsigned short* pre  = Qp;
  // K/V live in d_out (exactly 64 MiB); d_out fully rewritten by norm_scale.
  unsigned short* Kp  = (unsigned short*)d_out;
  unsigned short* Vp  = (unsigned short*)d_out + 16777216;

  xnorm_t<<<1024, 256, 0, stream>>>(x, xnT);
  cast_wqkv<<<3072, 256, 0, stream>>>(w_qkv, g_in, wqb);
  cast_w<<<1024, 256, 0, stream>>>(w_out, wob, 262144);
  gemm_bt<1536, true, false><<<dim3(96, 32), 256, 0, stream>>>(
      wqb, xnT, Qp, Kp, Vp, nullptr);
  attn_kernel<<<256, 256, 0, stream>>>(Qp, Kp, Vp, memkv, outT);
  gemm_bt<512, false, true><<<dim3(32, 32), 256, 0, stream>>>(
      wob, outT, pre, nullptr, nullptr, b_out);
  norm_scale<<<512, 256, 0, stream>>>(pre, g_out, out);
}